// Round 2
// baseline (3269.654 us; speedup 1.0000x reference)
//
#include <hip/hip_runtime.h>
#include <hip/hip_bf16.h>

#define IN_CH 256
#define OUT_CH 128
#define NUM_REL 8
#define NUM_BASES 4

// ---------------------------------------------------------------------------
// Kernel 1: w[r,i,o] = sum_b att[r,b] * basis[b,i,o]   -> ws  [8,256,128] f32
// ---------------------------------------------------------------------------
__global__ __launch_bounds__(256) void k_build_w(
    const float* __restrict__ att,     // [8,4]
    const float* __restrict__ basis,   // [4,256,128]
    float* __restrict__ w)             // [8,256,128]
{
    const int idx = blockIdx.x * 256 + threadIdx.x;   // < 8*32768
    const int r  = idx >> 15;
    const int io = idx & 32767;
    const float a0 = att[r * NUM_BASES + 0];
    const float a1 = att[r * NUM_BASES + 1];
    const float a2 = att[r * NUM_BASES + 2];
    const float a3 = att[r * NUM_BASES + 3];
    const int S = IN_CH * OUT_CH; // 32768
    w[idx] = a0 * basis[io] + a1 * basis[S + io] + a2 * basis[2 * S + io]
           + a3 * basis[3 * S + io];
}

// ---------------------------------------------------------------------------
// Kernel 2: dst[j] = x @ Wbase[j]  (+bias if addBias), j = blockIdx.y
// f32 vector-ALU GEMM. 256x128 tile, 256 threads, 16x8 per thread.
// Per kk: 6 ds_read_b128 per thread vs 128 FMAs -> ~1.3x LDS-bound (vs 1.9x
// for the 8x8 variant).
// ---------------------------------------------------------------------------
__global__ __launch_bounds__(256) void k_gemm(
    const float* __restrict__ x,      // [N,256]
    const float* __restrict__ Wbase,  // [gridDim.y,256,128]
    const float* __restrict__ bias,   // [128] (read only if addBias)
    float* __restrict__ dst,          // [gridDim.y,N,128]
    int N, int addBias)
{
    const int rr   = blockIdx.y;
    const float* __restrict__ W = Wbase + (size_t)rr * (IN_CH * OUT_CH);
    float* __restrict__ D = dst + (size_t)rr * N * OUT_CH;
    const int row0 = blockIdx.x * 256;

    // xs transposed [k][row]; pad row dim to 260 (keeps float4 alignment,
    // 2-way-max bank aliasing on both write and read -> free per m136)
    __shared__ float xs[16][260];
    __shared__ float wsm[16][128];

    const int tid = threadIdx.x;
    const int tx  = tid & 15;     // col group: cols tx*8 .. +7
    const int ty  = tid >> 4;     // row group: rows ty*16 .. +15

    float acc[16][8];
#pragma unroll
    for (int i = 0; i < 16; ++i)
#pragma unroll
        for (int j = 0; j < 8; ++j) acc[i][j] = 0.f;

    // staging indices
    const int lr = tid >> 2;          // 0..63
    const int lc = (tid & 3) * 4;     // k offset {0,4,8,12}

    for (int k0 = 0; k0 < IN_CH; k0 += 16) {
        // stage x tile: 256 rows x 16 k (transposed into xs[k][row])
#pragma unroll
        for (int half = 0; half < 4; ++half) {
            const int rloc = lr + half * 64;
            const int row  = row0 + rloc;
            float4 xv = make_float4(0.f, 0.f, 0.f, 0.f);
            if (row < N)
                xv = *(const float4*)(x + (size_t)row * IN_CH + k0 + lc);
            xs[lc + 0][rloc] = xv.x;
            xs[lc + 1][rloc] = xv.y;
            xs[lc + 2][rloc] = xv.z;
            xs[lc + 3][rloc] = xv.w;
        }
        // stage w tile: 16 k x 128 cols (thread (ty,tx) -> k=ty, cols tx*8..+7)
        {
            const float* wp = W + (size_t)(k0 + ty) * OUT_CH + tx * 8;
            const float4 wv0 = *(const float4*)(wp);
            const float4 wv1 = *(const float4*)(wp + 4);
            *(float4*)&wsm[ty][tx * 8]     = wv0;
            *(float4*)&wsm[ty][tx * 8 + 4] = wv1;
        }
        __syncthreads();

#pragma unroll
        for (int kk = 0; kk < 16; ++kk) {
            const float4 wa = *(const float4*)&wsm[kk][tx * 8];
            const float4 wb = *(const float4*)&wsm[kk][tx * 8 + 4];
            const float4 x0 = *(const float4*)&xs[kk][ty * 16];
            const float4 x1 = *(const float4*)&xs[kk][ty * 16 + 4];
            const float4 x2 = *(const float4*)&xs[kk][ty * 16 + 8];
            const float4 x3 = *(const float4*)&xs[kk][ty * 16 + 12];
            const float xv[16] = {x0.x, x0.y, x0.z, x0.w, x1.x, x1.y, x1.z, x1.w,
                                  x2.x, x2.y, x2.z, x2.w, x3.x, x3.y, x3.z, x3.w};
            const float wv[8]  = {wa.x, wa.y, wa.z, wa.w, wb.x, wb.y, wb.z, wb.w};
#pragma unroll
            for (int i = 0; i < 16; ++i)
#pragma unroll
                for (int j = 0; j < 8; ++j)
                    acc[i][j] = fmaf(xv[i], wv[j], acc[i][j]);
        }
        __syncthreads();
    }

    // epilogue
    float4 b0 = make_float4(0.f, 0.f, 0.f, 0.f);
    float4 b1 = make_float4(0.f, 0.f, 0.f, 0.f);
    if (addBias) {
        b0 = *(const float4*)(bias + tx * 8);
        b1 = *(const float4*)(bias + tx * 8 + 4);
    }
#pragma unroll
    for (int i = 0; i < 16; ++i) {
        const int row = row0 + ty * 16 + i;
        if (row < N) {
            float4 o0 = {acc[i][0] + b0.x, acc[i][1] + b0.y,
                         acc[i][2] + b0.z, acc[i][3] + b0.w};
            float4 o1 = {acc[i][4] + b1.x, acc[i][5] + b1.y,
                         acc[i][6] + b1.z, acc[i][7] + b1.w};
            float* op = D + (size_t)row * OUT_CH + tx * 8;
            *(float4*)(op)     = o0;
            *(float4*)(op + 4) = o1;
        }
    }
}

// ---------------------------------------------------------------------------
// Kernel 3: for edges with type in [r0,r1): out[dst] += norm * h[type-r0, src]
// 32 lanes per edge, float4 per lane, EPG edges per lane-group.
// ---------------------------------------------------------------------------
#define EPG 8
__global__ __launch_bounds__(256) void k_scatter(
    const float* __restrict__ h,      // [r1-r0, N, 128]
    const int*   __restrict__ esrc,
    const int*   __restrict__ edst,
    const int*   __restrict__ etype,
    const float* __restrict__ norm,
    float* __restrict__ out,          // [N,128]
    int E, int N, int r0, int r1)
{
    const int gid = blockIdx.x * 256 + threadIdx.x;
    const int l   = gid & 31;                 // lane within 32-lane group
    const int e0  = (gid >> 5) * EPG;
#pragma unroll
    for (int i = 0; i < EPG; ++i) {
        const int e = e0 + i;
        if (e >= E) break;                    // group-uniform
        const int t = etype[e];
        if (t < r0 || t >= r1) continue;      // group-uniform
        const int   src = esrc[e];
        const int   dst = edst[e];
        const float nm  = norm[e];
        const float4 v = *(const float4*)(
            h + (((size_t)(t - r0) * N + src) << 7) + l * 4);
        float* op = out + ((size_t)dst << 7) + l * 4;
        unsafeAtomicAdd(op + 0, v.x * nm);
        unsafeAtomicAdd(op + 1, v.y * nm);
        unsafeAtomicAdd(op + 2, v.z * nm);
        unsafeAtomicAdd(op + 3, v.w * nm);
    }
}

// ---------------------------------------------------------------------------
extern "C" void kernel_launch(void* const* d_in, const int* in_sizes, int n_in,
                              void* d_out, int out_size, void* d_ws, size_t ws_size,
                              hipStream_t stream) {
    const float* x     = (const float*)d_in[0];
    const int*   esrc  = (const int*)d_in[1];
    const int*   edst  = (const int*)d_in[2];
    const int*   etype = (const int*)d_in[3];
    const float* norm  = (const float*)d_in[4];
    const float* basis = (const float*)d_in[5];
    const float* att   = (const float*)d_in[6];
    const float* root  = (const float*)d_in[7];
    const float* bias  = (const float*)d_in[8];
    float* out = (float*)d_out;

    const int N = in_sizes[0] / IN_CH;
    const int E = in_sizes[1];

    const size_t wBytes  = (size_t)NUM_REL * IN_CH * OUT_CH * sizeof(float); // 1MB
    const size_t perRel  = (size_t)N * OUT_CH * sizeof(float);               // 25.6MB
    float* w = (float*)d_ws;
    float* h = (float*)((char*)d_ws + wBytes);

    // relation chunking: fit in ws, and cap at 4 so the per-pass working set
    // (h-chunk 102MB + x 51MB + out 26MB + edges 26MB) stays L3-resident.
    int CR = 4;
    if (ws_size > wBytes) {
        const size_t fit = (ws_size - wBytes) / perRel;
        if (fit < (size_t)CR) CR = (int)fit;
    } else {
        CR = 1;
    }
    if (CR < 1) CR = 1;

    const int nb = (N + 255) / 256;

    // 1. build per-relation weights
    k_build_w<<<(NUM_REL * IN_CH * OUT_CH) / 256, 256, 0, stream>>>(att, basis, w);

    // 2. out = x @ root + bias
    k_gemm<<<dim3(nb, 1), 256, 0, stream>>>(x, root, bias, out, N, 1);

    // 3. per relation-chunk: h = x @ w[r0:r1], then scatter edges of those types
    const int sblocks = ((E + EPG - 1) / EPG * 32 + 255) / 256;
    for (int rr0 = 0; rr0 < NUM_REL; rr0 += CR) {
        const int cr = (NUM_REL - rr0 < CR) ? (NUM_REL - rr0) : CR;
        k_gemm<<<dim3(nb, cr), 256, 0, stream>>>(
            x, w + (size_t)rr0 * IN_CH * OUT_CH, bias, h, N, 0);
        k_scatter<<<sblocks, 256, 0, stream>>>(
            h, esrc, edst, etype, norm, out, E, N, rr0, rr0 + cr);
    }
}

// Round 5
// 778.795 us; speedup vs baseline: 4.1983x; 4.1983x over previous
//
#include <hip/hip_runtime.h>

#define IN_CH 256
#define OUT_CH 128
#define NUM_REL 8
#define NUM_BASES 4
#define KCAT 512            // stored K (hi|lo) for xcat / wT
#define NSTEP 24            // virtual K = 768 = 24 * 32

typedef __bf16 bf16x8 __attribute__((ext_vector_type(8)));
typedef float  f32x4  __attribute__((ext_vector_type(4)));
typedef short  s16x8  __attribute__((ext_vector_type(8)));

typedef const __attribute__((address_space(1))) unsigned int* gas_u32p;
typedef __attribute__((address_space(3))) unsigned int*       las_u32p;
#define GLOAD16(g, l) __builtin_amdgcn_global_load_lds( \
    (gas_u32p)(const void*)(g), (las_u32p)(void*)(l), 16, 0, 0)

__device__ __forceinline__ unsigned short f2bf(float f) {
    unsigned u = __float_as_uint(f);
    return (unsigned short)((u + 0x7FFFu + ((u >> 16) & 1u)) >> 16);  // RNE
}
__device__ __forceinline__ float bf2f(unsigned short b) {
    return __uint_as_float(((unsigned)b) << 16);
}

// ---------------------------------------------------------------------------
// wT[r][o][k] bf16: k<256 -> hi(w[r][k][o]), k>=256 -> lo. r==8 is root.
// ---------------------------------------------------------------------------
__global__ __launch_bounds__(256) void k_build_wT(
    const float* __restrict__ att, const float* __restrict__ basis,
    const float* __restrict__ root, short* __restrict__ wT)
{
    const int idx = blockIdx.x * 256 + threadIdx.x;   // < 9*32768
    const int r = idx >> 15, io = idx & 32767;
    const int i = io >> 7, o = io & 127;
    float v;
    if (r < NUM_REL) {
        const int S = IN_CH * OUT_CH;
        v = att[r*4+0]*basis[io] + att[r*4+1]*basis[S+io]
          + att[r*4+2]*basis[2*S+io] + att[r*4+3]*basis[3*S+io];
    } else {
        v = root[io];
    }
    const unsigned short hi = f2bf(v);
    const unsigned short lo = f2bf(v - bf2f(hi));
    const size_t base = ((size_t)r * OUT_CH + o) * KCAT;
    wT[base + i]       = (short)hi;
    wT[base + 256 + i] = (short)lo;
}

// ---------------------------------------------------------------------------
// xcat[n][k] bf16: k<256 -> hi(x[n][k]), k>=256 -> lo
// ---------------------------------------------------------------------------
__global__ __launch_bounds__(256) void k_split_x(
    const float* __restrict__ x, short* __restrict__ xcat, int total)
{
    const int idx = blockIdx.x * 256 + threadIdx.x;
    if (idx >= total) return;
    const int n = idx >> 8, i = idx & 255;
    const float v = x[idx];
    const unsigned short hi = f2bf(v);
    const unsigned short lo = f2bf(v - bf2f(hi));
    const size_t base = (size_t)n * KCAT;
    xcat[base + i]       = (short)hi;
    xcat[base + 256 + i] = (short)lo;
}

// ---------------------------------------------------------------------------
// MFMA GEMM: D[rr] = split_f32(x @ w[rr]) (+bias). m97 structure: 128^2 tile,
// BK=32, 4 waves x (4x4) 16x16x32_bf16 frags, global_load_lds w16, linear LDS.
// Virtual K=768 over stored K=512:
//   vk in [0,256):   x_hi*w_hi   acol=vk      bcol=vk
//   vk in [256,512): x_lo*w_hi   acol=vk      bcol=vk-256
//   vk in [512,768): x_hi*w_lo   acol=vk-512  bcol=vk-256
// ---------------------------------------------------------------------------
__global__ __launch_bounds__(256) void k_mm(
    const short* __restrict__ xcat,   // [N][512]
    const short* __restrict__ wTb,    // [gridDim.y][128][512]
    const float* __restrict__ bias,   // [128] (if addBias)
    float* __restrict__ dst,          // [gridDim.y][N][128]
    int N, int addBias)
{
    const int rr = blockIdx.y;
    const short* __restrict__ Wt = wTb + (size_t)rr * OUT_CH * KCAT;
    float* __restrict__ D = dst + (size_t)rr * N * OUT_CH;
    const int row0 = blockIdx.x * 128;

    __shared__ short As[128 * 32];   // [row][k] 8KB
    __shared__ short Bs[128 * 32];   // [col][k] 8KB

    const int tid  = threadIdx.x;
    const int lane = tid & 63;
    const int wv   = tid >> 6;       // 0..3
    const int wr   = wv >> 1;        // row half of 128
    const int wc   = wv & 1;         // col half of 128
    const int lrow = lane & 15;
    const int q    = lane >> 4;      // k-quadrant 0..3

    f32x4 acc[4][4];
#pragma unroll
    for (int m = 0; m < 4; ++m)
#pragma unroll
        for (int n = 0; n < 4; ++n) acc[m][n] = f32x4{0.f, 0.f, 0.f, 0.f};

    for (int s = 0; s < NSTEP; ++s) {
        const int vk   = s * 32;
        const int acol = (vk < KCAT) ? vk : vk - KCAT;
        const int bcol = (vk < 256)  ? vk : vk - 256;
        __syncthreads();   // previous tile fully consumed before overwrite
#pragma unroll
        for (int i = 0; i < 2; ++i) {
            const int c = tid + i * 256;         // 16B chunk 0..511
            const int trow = c >> 2, slot = c & 3;
            int grow = row0 + trow; if (grow >= N) grow = N - 1;
            GLOAD16(xcat + (size_t)grow * KCAT + acol + slot * 8, As + c * 8);
            GLOAD16(Wt   + (size_t)trow * KCAT + bcol + slot * 8, Bs + c * 8);
        }
        __syncthreads();   // drains vmcnt -> tiles visible

        s16x8 af[4], bg[4];
#pragma unroll
        for (int m = 0; m < 4; ++m)
            af[m] = *(const s16x8*)&As[(wr * 64 + m * 16 + lrow) * 32 + q * 8];
#pragma unroll
        for (int n = 0; n < 4; ++n)
            bg[n] = *(const s16x8*)&Bs[(wc * 64 + n * 16 + lrow) * 32 + q * 8];
#pragma unroll
        for (int m = 0; m < 4; ++m)
#pragma unroll
            for (int n = 0; n < 4; ++n)
                acc[m][n] = __builtin_amdgcn_mfma_f32_16x16x32_bf16(
                    __builtin_bit_cast(bf16x8, af[m]),
                    __builtin_bit_cast(bf16x8, bg[n]), acc[m][n], 0, 0, 0);
    }

    // epilogue: C/D layout col=lane&15, row=(lane>>4)*4+j  [m89-verified]
    float bv[4] = {0.f, 0.f, 0.f, 0.f};
    if (addBias) {
#pragma unroll
        for (int n = 0; n < 4; ++n) bv[n] = bias[wc * 64 + n * 16 + lrow];
    }
#pragma unroll
    for (int m = 0; m < 4; ++m) {
#pragma unroll
        for (int j = 0; j < 4; ++j) {
            const int row = row0 + wr * 64 + m * 16 + q * 4 + j;
            if (row < N) {
#pragma unroll
                for (int n = 0; n < 4; ++n)
                    D[(size_t)row * OUT_CH + wc * 64 + n * 16 + lrow] =
                        acc[m][n][j] + bv[n];
            }
        }
    }
}

// ---------------------------------------------------------------------------
// CSR build: zero -> hist -> scan -> copy cursor -> fill
// ---------------------------------------------------------------------------
__global__ __launch_bounds__(256) void k_zero(int* __restrict__ p, int n) {
    const int i = blockIdx.x * 256 + threadIdx.x;
    if (i < n) p[i] = 0;
}

__global__ __launch_bounds__(256) void k_hist(
    const int* __restrict__ edst, int* __restrict__ deg, int E) {
    const int e = blockIdx.x * 256 + threadIdx.x;
    if (e < E) atomicAdd(&deg[edst[e]], 1);
}

__global__ __launch_bounds__(1024) void k_scan(
    const int* __restrict__ deg, int* __restrict__ offsets, int N) {
    __shared__ int wsum[16];
    __shared__ int basesm;
    const int tid = threadIdx.x, lane = tid & 63, wid = tid >> 6;
    if (tid == 0) { basesm = 0; offsets[0] = 0; }
    __syncthreads();
    for (int c = 0; c < N; c += 1024) {
        const int i = c + tid;
        int s = (i < N) ? deg[i] : 0;
#pragma unroll
        for (int d = 1; d < 64; d <<= 1) {
            const int t = __shfl_up(s, d);
            if (lane >= d) s += t;
        }
        if (lane == 63) wsum[wid] = s;
        __syncthreads();
        int wprefix = 0;
#pragma unroll
        for (int wj = 0; wj < 15; ++wj) wprefix += (wj < wid) ? wsum[wj] : 0;
        const int base = basesm;
        if (i < N) offsets[i + 1] = base + wprefix + s;
        __syncthreads();
        if (tid == 0) {
            int tot = 0;
#pragma unroll
            for (int wj = 0; wj < 16; ++wj) tot += wsum[wj];
            basesm = base + tot;
        }
        __syncthreads();
    }
}

__global__ __launch_bounds__(256) void k_copy(
    const int* __restrict__ a, int* __restrict__ b, int n) {
    const int i = blockIdx.x * 256 + threadIdx.x;
    if (i < n) b[i] = a[i];
}

__global__ __launch_bounds__(256) void k_fill(
    const int* __restrict__ esrc, const int* __restrict__ edst,
    const int* __restrict__ etype, const float* __restrict__ norm,
    int* __restrict__ cursor, int* __restrict__ pkey,
    float* __restrict__ pnorm, int E) {
    const int e = blockIdx.x * 256 + threadIdx.x;
    if (e >= E) return;
    const int d = edst[e];
    const int pos = atomicAdd(&cursor[d], 1);
    pkey[pos]  = esrc[e] | (etype[e] << 27);
    pnorm[pos] = norm[e];
}

// ---------------------------------------------------------------------------
// Gather: one 64-lane wave per dst node; accumulate edges with type in
// [r0,r1) from h chunk; single non-atomic RMW of out[dst] (wave owns row).
// All control values (s,e,key) are wave-uniform -> no divergence.
// ---------------------------------------------------------------------------
__global__ __launch_bounds__(256) void k_gather(
    const float* __restrict__ h,        // [r1-r0, N, 128]
    const int*   __restrict__ offsets,  // [N+1]
    const int*   __restrict__ pkey,     // [E]
    const float* __restrict__ pnorm,    // [E]
    float* __restrict__ out,            // [N,128]
    int N, int r0, int r1)
{
    const int wid  = blockIdx.x * 4 + (threadIdx.x >> 6);
    if (wid >= N) return;
    const int lane = threadIdx.x & 63;
    const int s = offsets[wid];
    const int e = offsets[wid + 1];
    float2 acc = {0.f, 0.f};
    bool any = false;
#pragma unroll 4
    for (int p = s; p < e; ++p) {
        const int key = pkey[p];
        const int t = key >> 27;
        if (t < r0 || t >= r1) continue;   // wave-uniform
        any = true;
        const int src = key & 0x07FFFFFF;
        const float nm = pnorm[p];
        const float2 v = *(const float2*)(
            h + (((size_t)(t - r0) * N + src) << 7) + lane * 2);
        acc.x = fmaf(v.x, nm, acc.x);
        acc.y = fmaf(v.y, nm, acc.y);
    }
    if (any) {
        float* op = out + ((size_t)wid << 7) + lane * 2;
        float2 cur = *(const float2*)op;
        cur.x += acc.x;
        cur.y += acc.y;
        *(float2*)op = cur;
    }
}

// ---------------------------------------------------------------------------
extern "C" void kernel_launch(void* const* d_in, const int* in_sizes, int n_in,
                              void* d_out, int out_size, void* d_ws, size_t ws_size,
                              hipStream_t stream) {
    const float* x     = (const float*)d_in[0];
    const int*   esrc  = (const int*)d_in[1];
    const int*   edst  = (const int*)d_in[2];
    const int*   etype = (const int*)d_in[3];
    const float* norm  = (const float*)d_in[4];
    const float* basis = (const float*)d_in[5];
    const float* att   = (const float*)d_in[6];
    const float* root  = (const float*)d_in[7];
    const float* bias  = (const float*)d_in[8];
    float* out = (float*)d_out;

    const int N = in_sizes[0] / IN_CH;
    const int E = in_sizes[1];

    // ---- workspace layout ----
    short* wT   = (short*)d_ws;                       // 9*128*512*2 = 1.18MB
    short* xcat = wT + (size_t)9 * OUT_CH * KCAT;     // N*512*2    = 51.2MB
    int* deg     = (int*)(xcat + (size_t)N * KCAT);
    int* offsets = deg + N;
    int* cursor  = offsets + N + 1;
    int* pkey    = cursor + N;
    float* pnorm = (float*)(pkey + E);
    size_t hoff = (size_t)((char*)(pnorm + E) - (char*)d_ws);
    hoff = (hoff + 255) & ~(size_t)255;
    float* h = (float*)((char*)d_ws + hoff);

    const size_t perRel = (size_t)N * OUT_CH * 4;     // 25.6 MB
    int CR = 4;                                       // keep chunk L3-resident
    {
        const size_t avail = (ws_size > hoff) ? (ws_size - hoff) : 0;
        const size_t fit = avail / perRel;
        if (fit < (size_t)CR) CR = (int)fit;
        if (CR < 1) CR = 1;
    }

    const int nbN = (N + 255) / 256;
    const int nbE = (E + 255) / 256;
    const int nbG = (N + 127) / 128;                  // gemm row-blocks

    // 1. weights (hi|lo, transposed) and x split
    k_build_wT<<<(9 * IN_CH * OUT_CH) / 256, 256, 0, stream>>>(att, basis, root, wT);
    k_split_x<<<(N * IN_CH + 255) / 256, 256, 0, stream>>>(x, xcat, N * IN_CH);

    // 2. CSR build
    k_zero<<<nbN, 256, 0, stream>>>(deg, N);
    k_hist<<<nbE, 256, 0, stream>>>(edst, deg, E);
    k_scan<<<1, 1024, 0, stream>>>(deg, offsets, N);
    k_copy<<<nbN, 256, 0, stream>>>(offsets, cursor, N);
    k_fill<<<nbE, 256, 0, stream>>>(esrc, edst, etype, norm, cursor, pkey, pnorm, E);

    // 3. out = x @ root + bias   (relation index 8 in wT)
    k_mm<<<dim3(nbG, 1), 256, 0, stream>>>(
        xcat, wT + (size_t)NUM_REL * OUT_CH * KCAT, bias, out, N, 1);

    // 4. per relation-chunk: h = x @ w[r0:r1]; gather into out
    const int gblocks = (N + 3) / 4;
    for (int rr0 = 0; rr0 < NUM_REL; rr0 += CR) {
        const int cr = (NUM_REL - rr0 < CR) ? (NUM_REL - rr0) : CR;
        k_mm<<<dim3(nbG, cr), 256, 0, stream>>>(
            xcat, wT + (size_t)rr0 * OUT_CH * KCAT, bias, h, N, 0);
        k_gather<<<gblocks, 256, 0, stream>>>(
            h, offsets, pkey, pnorm, out, N, rr0, rr0 + cr);
    }
}

// Round 6
// 581.872 us; speedup vs baseline: 5.6192x; 1.3384x over previous
//
#include <hip/hip_runtime.h>

#define IN_CH 256
#define OUT_CH 128
#define NUM_REL 8
#define NUM_BASES 4
#define KCAT 512            // stored K (hi|lo) for xcat / wT
#define NSTEP 24            // virtual K = 768 = 24 * 32

typedef __bf16 bf16x8 __attribute__((ext_vector_type(8)));
typedef float  f32x4  __attribute__((ext_vector_type(4)));
typedef short  s16x8  __attribute__((ext_vector_type(8)));

typedef const __attribute__((address_space(1))) unsigned int* gas_u32p;
typedef __attribute__((address_space(3))) unsigned int*       las_u32p;
#define GLOAD16(g, l) __builtin_amdgcn_global_load_lds( \
    (gas_u32p)(const void*)(g), (las_u32p)(void*)(l), 16, 0, 0)

__device__ __forceinline__ unsigned short f2bf(float f) {
    unsigned u = __float_as_uint(f);
    return (unsigned short)((u + 0x7FFFu + ((u >> 16) & 1u)) >> 16);  // RNE
}
__device__ __forceinline__ float bf2f(unsigned short b) {
    return __uint_as_float(((unsigned)b) << 16);
}

// ---------------------------------------------------------------------------
// wT[r][o][k] bf16: k<256 -> hi(w[r][k][o]), k>=256 -> lo. r==8 is root.
// ---------------------------------------------------------------------------
__global__ __launch_bounds__(256) void k_build_wT(
    const float* __restrict__ att, const float* __restrict__ basis,
    const float* __restrict__ root, short* __restrict__ wT)
{
    const int idx = blockIdx.x * 256 + threadIdx.x;   // < 9*32768
    const int r = idx >> 15, io = idx & 32767;
    const int i = io >> 7, o = io & 127;
    float v;
    if (r < NUM_REL) {
        const int S = IN_CH * OUT_CH;
        v = att[r*4+0]*basis[io] + att[r*4+1]*basis[S+io]
          + att[r*4+2]*basis[2*S+io] + att[r*4+3]*basis[3*S+io];
    } else {
        v = root[io];
    }
    const unsigned short hi = f2bf(v);
    const unsigned short lo = f2bf(v - bf2f(hi));
    const size_t base = ((size_t)r * OUT_CH + o) * KCAT;
    wT[base + i]       = (short)hi;
    wT[base + 256 + i] = (short)lo;
}

// ---------------------------------------------------------------------------
// xcat[n][k] bf16: k<256 -> hi(x[n][k]), k>=256 -> lo
// ---------------------------------------------------------------------------
__global__ __launch_bounds__(256) void k_split_x(
    const float* __restrict__ x, short* __restrict__ xcat, int total)
{
    const int idx = blockIdx.x * 256 + threadIdx.x;
    if (idx >= total) return;
    const int n = idx >> 8, i = idx & 255;
    const float v = x[idx];
    const unsigned short hi = f2bf(v);
    const unsigned short lo = f2bf(v - bf2f(hi));
    const size_t base = (size_t)n * KCAT;
    xcat[base + i]       = (short)hi;
    xcat[base + 256 + i] = (short)lo;
}

// ---------------------------------------------------------------------------
// MFMA GEMM (m97 structure: 128^2 tile, BK=32, 4 waves x 4x4 frags of
// 16x16x32_bf16, global_load_lds w16, linear LDS). Virtual K=768:
//   vk in [0,256):   x_hi*w_hi ; [256,512): x_lo*w_hi ; [512,768): x_hi*w_lo
// mode 0: Df32[row][col] = acc + bias   (root -> out)
// mode 1: D16[rr][row][col] = bf16(acc) (h, no bias)
// ---------------------------------------------------------------------------
__global__ __launch_bounds__(256) void k_mm(
    const short* __restrict__ xcat,   // [N][512]
    const short* __restrict__ wTb,    // [gridDim.y][128][512]
    const float* __restrict__ bias,
    float* __restrict__ Df32,
    unsigned short* __restrict__ D16,
    int N, int mode)
{
    const int rr = blockIdx.y;
    const short* __restrict__ Wt = wTb + (size_t)rr * OUT_CH * KCAT;
    const int row0 = blockIdx.x * 128;

    __shared__ short As[128 * 32];   // [row][k] 8KB
    __shared__ short Bs[128 * 32];   // [col][k] 8KB

    const int tid  = threadIdx.x;
    const int lane = tid & 63;
    const int wv   = tid >> 6;
    const int wr   = wv >> 1;
    const int wc   = wv & 1;
    const int lrow = lane & 15;
    const int q    = lane >> 4;

    f32x4 acc[4][4];
#pragma unroll
    for (int m = 0; m < 4; ++m)
#pragma unroll
        for (int n = 0; n < 4; ++n) acc[m][n] = f32x4{0.f, 0.f, 0.f, 0.f};

    for (int s = 0; s < NSTEP; ++s) {
        const int vk   = s * 32;
        const int acol = (vk < KCAT) ? vk : vk - KCAT;
        const int bcol = (vk < 256)  ? vk : vk - 256;
        __syncthreads();
#pragma unroll
        for (int i = 0; i < 2; ++i) {
            const int c = tid + i * 256;
            const int trow = c >> 2, slot = c & 3;
            int grow = row0 + trow; if (grow >= N) grow = N - 1;
            GLOAD16(xcat + (size_t)grow * KCAT + acol + slot * 8, As + c * 8);
            GLOAD16(Wt   + (size_t)trow * KCAT + bcol + slot * 8, Bs + c * 8);
        }
        __syncthreads();

        s16x8 af[4], bg[4];
#pragma unroll
        for (int m = 0; m < 4; ++m)
            af[m] = *(const s16x8*)&As[(wr * 64 + m * 16 + lrow) * 32 + q * 8];
#pragma unroll
        for (int n = 0; n < 4; ++n)
            bg[n] = *(const s16x8*)&Bs[(wc * 64 + n * 16 + lrow) * 32 + q * 8];
#pragma unroll
        for (int m = 0; m < 4; ++m)
#pragma unroll
            for (int n = 0; n < 4; ++n)
                acc[m][n] = __builtin_amdgcn_mfma_f32_16x16x32_bf16(
                    __builtin_bit_cast(bf16x8, af[m]),
                    __builtin_bit_cast(bf16x8, bg[n]), acc[m][n], 0, 0, 0);
    }

    // C/D layout: col=lane&15, row=(lane>>4)*4+j  [m89-verified]
    if (mode == 0) {
        float bv[4];
#pragma unroll
        for (int n = 0; n < 4; ++n) bv[n] = bias[wc * 64 + n * 16 + lrow];
#pragma unroll
        for (int m = 0; m < 4; ++m)
#pragma unroll
            for (int j = 0; j < 4; ++j) {
                const int row = row0 + wr * 64 + m * 16 + q * 4 + j;
                if (row < N) {
#pragma unroll
                    for (int n = 0; n < 4; ++n)
                        Df32[(size_t)row * OUT_CH + wc * 64 + n * 16 + lrow] =
                            acc[m][n][j] + bv[n];
                }
            }
    } else {
        unsigned short* __restrict__ Dh = D16 + (size_t)rr * N * OUT_CH;
#pragma unroll
        for (int m = 0; m < 4; ++m)
#pragma unroll
            for (int j = 0; j < 4; ++j) {
                const int row = row0 + wr * 64 + m * 16 + q * 4 + j;
                if (row < N) {
#pragma unroll
                    for (int n = 0; n < 4; ++n)
                        Dh[(size_t)row * OUT_CH + wc * 64 + n * 16 + lrow] =
                            f2bf(acc[m][n][j]);
                }
            }
    }
}

// ---------------------------------------------------------------------------
// (dst,type)-binned CSR build over M8 = N*8 bins
// ---------------------------------------------------------------------------
__global__ __launch_bounds__(256) void k_zero(int* __restrict__ p, int n) {
    const int i = blockIdx.x * 256 + threadIdx.x;
    if (i < n) p[i] = 0;
}

__global__ __launch_bounds__(256) void k_hist8(
    const int* __restrict__ edst, const int* __restrict__ etype,
    int* __restrict__ deg8, int E) {
    const int e = blockIdx.x * 256 + threadIdx.x;
    if (e < E) atomicAdd(&deg8[edst[e] * 8 + etype[e]], 1);
}

// phase A: per-block (1024 elems) inclusive scan -> oplus1; block totals
__global__ __launch_bounds__(256) void k_scan_blk(
    const int* __restrict__ deg, int* __restrict__ oplus1,
    int* __restrict__ btot, int M8)
{
    __shared__ int wsum[4];
    const int tid = threadIdx.x, lane = tid & 63, wv = tid >> 6;
    const int base = blockIdx.x * 1024 + tid * 4;
    int v[4]; int s = 0;
#pragma unroll
    for (int j = 0; j < 4; ++j) {
        v[j] = (base + j < M8) ? deg[base + j] : 0;
        s += v[j];
    }
    int sc = s;
#pragma unroll
    for (int d = 1; d < 64; d <<= 1) {
        const int t = __shfl_up(sc, d);
        if (lane >= d) sc += t;
    }
    if (lane == 63) wsum[wv] = sc;
    __syncthreads();
    int wpre = 0;
#pragma unroll
    for (int j = 0; j < 4; ++j) wpre += (j < wv) ? wsum[j] : 0;
    int run = wpre + sc - s;          // exclusive prefix of this thread
#pragma unroll
    for (int j = 0; j < 4; ++j) {
        run += v[j];
        if (base + j < M8) oplus1[base + j] = run;
    }
    if (tid == 255) btot[blockIdx.x] = run;  // block total
}

// phase B: exclusive scan of block totals (nblk <= 512)
__global__ __launch_bounds__(256) void k_scan_mid(
    const int* __restrict__ btot, int* __restrict__ bbase, int nblk)
{
    __shared__ int sm[512];
    const int tid = threadIdx.x;
    for (int i = tid; i < nblk; i += 256) sm[i] = btot[i];
    __syncthreads();
    if (tid == 0) {
        int run = 0;
        for (int i = 0; i < nblk; ++i) { const int t = sm[i]; sm[i] = run; run += t; }
    }
    __syncthreads();
    for (int i = tid; i < nblk; i += 256) bbase[i] = sm[i];
}

// phase C: add block bases; set offsets8[0]=0
__global__ __launch_bounds__(256) void k_scan_add(
    int* __restrict__ offsets8, const int* __restrict__ bbase, int M8)
{
    const int base = blockIdx.x * 1024 + threadIdx.x * 4;
    const int b = bbase[blockIdx.x];
#pragma unroll
    for (int j = 0; j < 4; ++j)
        if (base + j < M8) offsets8[base + j + 1] += b;
    if (blockIdx.x == 0 && threadIdx.x == 0) offsets8[0] = 0;
}

__global__ __launch_bounds__(256) void k_copy(
    const int* __restrict__ a, int* __restrict__ b, int n) {
    const int i = blockIdx.x * 256 + threadIdx.x;
    if (i < n) b[i] = a[i];
}

__global__ __launch_bounds__(256) void k_fill8(
    const int* __restrict__ esrc, const int* __restrict__ edst,
    const int* __restrict__ etype, const float* __restrict__ norm,
    int* __restrict__ cursor8, int* __restrict__ pkey,
    float* __restrict__ pnorm, int E) {
    const int e = blockIdx.x * 256 + threadIdx.x;
    if (e >= E) return;
    const int t = etype[e];
    const int pos = atomicAdd(&cursor8[edst[e] * 8 + t], 1);
    pkey[pos]  = esrc[e] | (t << 27);
    pnorm[pos] = norm[e];
}

// ---------------------------------------------------------------------------
// Gather: one wave per dst; walk only bins [r0,r1) (sorted CSR -> contiguous,
// zero type-filter). h is bf16; out RMW is non-atomic (wave owns row).
// ---------------------------------------------------------------------------
__global__ __launch_bounds__(256) void k_gather(
    const unsigned short* __restrict__ h,   // [r1-r0][N][128] bf16
    const int*   __restrict__ offsets8,     // [N*8+1]
    const int*   __restrict__ pkey,
    const float* __restrict__ pnorm,
    float* __restrict__ out,                // [N][128]
    int N, int r0, int r1)
{
    const int wid  = blockIdx.x * 4 + (threadIdx.x >> 6);
    if (wid >= N) return;
    const int lane = threadIdx.x & 63;
    const int s = offsets8[wid * 8 + r0];
    const int e = offsets8[wid * 8 + r1];
    if (e == s) return;
    float2 acc = {0.f, 0.f};
#pragma unroll 4
    for (int p = s; p < e; ++p) {
        const int key = pkey[p];
        const int t   = (key >> 27) - r0;
        const int src = key & 0x07FFFFFF;
        const float nm = pnorm[p];
        const unsigned vp = *(const unsigned*)(
            h + (((size_t)t * N + src) << 7) + lane * 2);
        acc.x = fmaf(bf2f((unsigned short)(vp & 0xFFFF)), nm, acc.x);
        acc.y = fmaf(bf2f((unsigned short)(vp >> 16)),    nm, acc.y);
    }
    float* op = out + ((size_t)wid << 7) + lane * 2;
    const float2 cur = *(const float2*)op;
    *(float2*)op = {cur.x + acc.x, cur.y + acc.y};
}

// ---------------------------------------------------------------------------
extern "C" void kernel_launch(void* const* d_in, const int* in_sizes, int n_in,
                              void* d_out, int out_size, void* d_ws, size_t ws_size,
                              hipStream_t stream) {
    const float* x     = (const float*)d_in[0];
    const int*   esrc  = (const int*)d_in[1];
    const int*   edst  = (const int*)d_in[2];
    const int*   etype = (const int*)d_in[3];
    const float* norm  = (const float*)d_in[4];
    const float* basis = (const float*)d_in[5];
    const float* att   = (const float*)d_in[6];
    const float* root  = (const float*)d_in[7];
    const float* bias  = (const float*)d_in[8];
    float* out = (float*)d_out;

    const int N  = in_sizes[0] / IN_CH;
    const int E  = in_sizes[1];
    const int M8 = N * 8;
    const int nblkA = (M8 + 1023) / 1024;

    // ---- workspace layout ----
    short* wT   = (short*)d_ws;                       // 1.18 MB
    short* xcat = wT + (size_t)9 * OUT_CH * KCAT;     // 51.2 MB
    int* deg8     = (int*)(xcat + (size_t)N * KCAT);  // 1.6 MB
    int* offsets8 = deg8 + M8;                        // 1.6 MB
    int* cursor8  = offsets8 + M8 + 1;                // 1.6 MB
    int* btot     = cursor8 + M8;
    int* bbase    = btot + nblkA;
    int* pkey     = bbase + nblkA;                    // 6.4 MB
    float* pnorm  = (float*)(pkey + E);               // 6.4 MB
    size_t hoff = (size_t)((char*)(pnorm + E) - (char*)d_ws);
    hoff = (hoff + 255) & ~(size_t)255;
    unsigned short* h = (unsigned short*)((char*)d_ws + hoff);

    const size_t perRel = (size_t)N * OUT_CH * 2;     // 12.8 MB (bf16)
    int CR = 4;                                       // chunk L3-resident
    {
        const size_t avail = (ws_size > hoff) ? (ws_size - hoff) : 0;
        const size_t fit = avail / perRel;
        if (fit < (size_t)CR) CR = (int)fit;
        if (CR < 1) CR = 1;
    }

    const int nbE  = (E + 255) / 256;
    const int nbM8 = (M8 + 255) / 256;
    const int nbG  = (N + 127) / 128;

    // 1. weights (hi|lo, transposed) and x split
    k_build_wT<<<(9 * IN_CH * OUT_CH) / 256, 256, 0, stream>>>(att, basis, root, wT);
    k_split_x<<<(N * IN_CH + 255) / 256, 256, 0, stream>>>(x, xcat, N * IN_CH);

    // 2. (dst,type)-sorted CSR
    k_zero<<<nbM8, 256, 0, stream>>>(deg8, M8);
    k_hist8<<<nbE, 256, 0, stream>>>(edst, etype, deg8, E);
    k_scan_blk<<<nblkA, 256, 0, stream>>>(deg8, offsets8 + 1, btot, M8);
    k_scan_mid<<<1, 256, 0, stream>>>(btot, bbase, nblkA);
    k_scan_add<<<nblkA, 256, 0, stream>>>(offsets8, bbase, M8);
    k_copy<<<nbM8, 256, 0, stream>>>(offsets8, cursor8, M8);
    k_fill8<<<nbE, 256, 0, stream>>>(esrc, edst, etype, norm, cursor8, pkey, pnorm, E);

    // 3. out = x @ root + bias   (relation index 8 in wT)
    k_mm<<<dim3(nbG, 1), 256, 0, stream>>>(
        xcat, wT + (size_t)NUM_REL * OUT_CH * KCAT, bias, out, (unsigned short*)0, N, 0);

    // 4. per relation-chunk: h = bf16(x @ w[r0:r1]); gather into out
    const int gblocks = (N + 3) / 4;
    for (int rr0 = 0; rr0 < NUM_REL; rr0 += CR) {
        const int cr = (NUM_REL - rr0 < CR) ? (NUM_REL - rr0) : CR;
        k_mm<<<dim3(nbG, cr), 256, 0, stream>>>(
            xcat, wT + (size_t)rr0 * OUT_CH * KCAT, bias, (float*)0, h, N, 1);
        k_gather<<<gblocks, 256, 0, stream>>>(
            h, offsets8, pkey, pnorm, out, N, rr0, rr0 + cr);
    }
}

// Round 8
// 535.390 us; speedup vs baseline: 6.1070x; 1.0868x over previous
//
#include <hip/hip_runtime.h>

#define IN_CH 256
#define OUT_CH 128
#define NUM_REL 8
#define NUM_BASES 4
#define KCAT 512            // stored K (hi|lo) for xcat / wT
#define NSTEP 24            // virtual K = 768 = 24 * 32

typedef __bf16 bf16x8 __attribute__((ext_vector_type(8)));
typedef float  f32x4  __attribute__((ext_vector_type(4)));
typedef short  s16x8  __attribute__((ext_vector_type(8)));

typedef const __attribute__((address_space(1))) unsigned int* gas_u32p;
typedef __attribute__((address_space(3))) unsigned int*       las_u32p;
#define GLOAD16(g, l) __builtin_amdgcn_global_load_lds( \
    (gas_u32p)(const void*)(g), (las_u32p)(void*)(l), 16, 0, 0)

__device__ __forceinline__ unsigned short f2bf(float f) {
    unsigned u = __float_as_uint(f);
    return (unsigned short)((u + 0x7FFFu + ((u >> 16) & 1u)) >> 16);  // RNE
}
__device__ __forceinline__ float bf2f(unsigned short b) {
    return __uint_as_float(((unsigned)b) << 16);
}

// ---------------------------------------------------------------------------
// wT[r][o][k] bf16: k<256 -> hi(w[r][k][o]), k>=256 -> lo. r==8 is root.
// ---------------------------------------------------------------------------
__global__ __launch_bounds__(256) void k_build_wT(
    const float* __restrict__ att, const float* __restrict__ basis,
    const float* __restrict__ root, short* __restrict__ wT)
{
    const int idx = blockIdx.x * 256 + threadIdx.x;   // < 9*32768
    const int r = idx >> 15, io = idx & 32767;
    const int i = io >> 7, o = io & 127;
    float v;
    if (r < NUM_REL) {
        const int S = IN_CH * OUT_CH;
        v = att[r*4+0]*basis[io] + att[r*4+1]*basis[S+io]
          + att[r*4+2]*basis[2*S+io] + att[r*4+3]*basis[3*S+io];
    } else {
        v = root[io];
    }
    const unsigned short hi = f2bf(v);
    const unsigned short lo = f2bf(v - bf2f(hi));
    const size_t base = ((size_t)r * OUT_CH + o) * KCAT;
    wT[base + i]       = (short)hi;
    wT[base + 256 + i] = (short)lo;
}

// ---------------------------------------------------------------------------
// xcat[n][k] bf16: k<256 -> hi(x[n][k]), k>=256 -> lo
// ---------------------------------------------------------------------------
__global__ __launch_bounds__(256) void k_split_x(
    const float* __restrict__ x, short* __restrict__ xcat, int total)
{
    const int idx = blockIdx.x * 256 + threadIdx.x;
    if (idx >= total) return;
    const int n = idx >> 8, i = idx & 255;
    const float v = x[idx];
    const unsigned short hi = f2bf(v);
    const unsigned short lo = f2bf(v - bf2f(hi));
    const size_t base = (size_t)n * KCAT;
    xcat[base + i]       = (short)hi;
    xcat[base + 256 + i] = (short)lo;
}

// ---------------------------------------------------------------------------
// MFMA GEMM, double-buffered LDS, ONE barrier per K-step (STAGE(next) issued
// before compute(cur); the barrier's vmcnt(0) drain lands after the MFMAs
// covered the load latency). 128^2 tile, BK=32, 4 waves x 4x4 16x16x32_bf16.
// Virtual K=768: [0,256) x_hi*w_hi ; [256,512) x_lo*w_hi ; [512,768) x_hi*w_lo
// Block with blockIdx.y==rootIdx writes f32+bias to Df32; others bf16 to D16.
// ---------------------------------------------------------------------------
__global__ __launch_bounds__(256) void k_mm(
    const short* __restrict__ xcat,   // [N][512]
    const short* __restrict__ wTb,    // [gridDim.y][128][512]
    const float* __restrict__ bias,
    float* __restrict__ Df32,         // [N][128] (root)
    unsigned short* __restrict__ D16, // [*][N][128] bf16 (h)
    int N, int rootIdx)
{
    const int rr = blockIdx.y;
    const short* __restrict__ Wt = wTb + (size_t)rr * OUT_CH * KCAT;
    const int row0 = blockIdx.x * 128;

    __shared__ short As[2][128 * 32];   // 2 x 8KB
    __shared__ short Bs[2][128 * 32];   // 2 x 8KB

    const int tid  = threadIdx.x;
    const int lane = tid & 63;
    const int wv   = tid >> 6;
    const int wr   = wv >> 1;
    const int wc   = wv & 1;
    const int lrow = lane & 15;
    const int q    = lane >> 4;

    f32x4 acc[4][4];
#pragma unroll
    for (int m = 0; m < 4; ++m)
#pragma unroll
        for (int n = 0; n < 4; ++n) acc[m][n] = f32x4{0.f, 0.f, 0.f, 0.f};

    auto STAGE = [&](int b, int s) {
        const int vk   = s * 32;
        const int acol = (vk < KCAT) ? vk : vk - KCAT;
        const int bcol = (vk < 256)  ? vk : vk - 256;
#pragma unroll
        for (int i = 0; i < 2; ++i) {
            const int c = tid + i * 256;         // 16B chunk 0..511
            const int trow = c >> 2, slot = c & 3;
            int grow = row0 + trow; if (grow >= N) grow = N - 1;
            GLOAD16(xcat + (size_t)grow * KCAT + acol + slot * 8, &As[b][c * 8]);
            GLOAD16(Wt   + (size_t)trow * KCAT + bcol + slot * 8, &Bs[b][c * 8]);
        }
    };

    STAGE(0, 0);
    __syncthreads();                    // drains vmcnt(0): buf0 ready

#pragma unroll 2
    for (int s = 0; s < NSTEP; ++s) {
        const int cur = s & 1;
        if (s + 1 < NSTEP) STAGE(cur ^ 1, s + 1);   // in flight during MFMA

        s16x8 af[4], bg[4];
#pragma unroll
        for (int m = 0; m < 4; ++m)
            af[m] = *(const s16x8*)&As[cur][(wr * 64 + m * 16 + lrow) * 32 + q * 8];
#pragma unroll
        for (int n = 0; n < 4; ++n)
            bg[n] = *(const s16x8*)&Bs[cur][(wc * 64 + n * 16 + lrow) * 32 + q * 8];
#pragma unroll
        for (int m = 0; m < 4; ++m)
#pragma unroll
            for (int n = 0; n < 4; ++n)
                acc[m][n] = __builtin_amdgcn_mfma_f32_16x16x32_bf16(
                    __builtin_bit_cast(bf16x8, af[m]),
                    __builtin_bit_cast(bf16x8, bg[n]), acc[m][n], 0, 0, 0);

        __syncthreads();   // cur fully consumed (lgkmcnt) + next buf drained
    }

    // C/D layout: col=lane&15, row=(lane>>4)*4+j  [m89-verified]
    if (rr == rootIdx) {
        float bv[4];
#pragma unroll
        for (int n = 0; n < 4; ++n) bv[n] = bias[wc * 64 + n * 16 + lrow];
#pragma unroll
        for (int m = 0; m < 4; ++m)
#pragma unroll
            for (int j = 0; j < 4; ++j) {
                const int row = row0 + wr * 64 + m * 16 + q * 4 + j;
                if (row < N) {
#pragma unroll
                    for (int n = 0; n < 4; ++n)
                        Df32[(size_t)row * OUT_CH + wc * 64 + n * 16 + lrow] =
                            acc[m][n][j] + bv[n];
                }
            }
    } else {
        unsigned short* __restrict__ Dh = D16 + (size_t)rr * N * OUT_CH;
#pragma unroll
        for (int m = 0; m < 4; ++m)
#pragma unroll
            for (int j = 0; j < 4; ++j) {
                const int row = row0 + wr * 64 + m * 16 + q * 4 + j;
                if (row < N) {
#pragma unroll
                    for (int n = 0; n < 4; ++n)
                        Dh[(size_t)row * OUT_CH + wc * 64 + n * 16 + lrow] =
                            f2bf(acc[m][n][j]);
                }
            }
    }
}

// ---------------------------------------------------------------------------
// (dst,type)-binned CSR build over M8 = N*8 bins
// ---------------------------------------------------------------------------
__global__ __launch_bounds__(256) void k_zero(int* __restrict__ p, int n) {
    const int i = blockIdx.x * 256 + threadIdx.x;
    if (i < n) p[i] = 0;
}

__global__ __launch_bounds__(256) void k_hist8(
    const int* __restrict__ edst, const int* __restrict__ etype,
    int* __restrict__ deg8, int E) {
    const int e = blockIdx.x * 256 + threadIdx.x;
    if (e < E) atomicAdd(&deg8[edst[e] * 8 + etype[e]], 1);
}

__global__ __launch_bounds__(256) void k_scan_blk(
    const int* __restrict__ deg, int* __restrict__ oplus1,
    int* __restrict__ btot, int M8)
{
    __shared__ int wsum[4];
    const int tid = threadIdx.x, lane = tid & 63, wv = tid >> 6;
    const int base = blockIdx.x * 1024 + tid * 4;
    int v[4]; int s = 0;
#pragma unroll
    for (int j = 0; j < 4; ++j) {
        v[j] = (base + j < M8) ? deg[base + j] : 0;
        s += v[j];
    }
    int sc = s;
#pragma unroll
    for (int d = 1; d < 64; d <<= 1) {
        const int t = __shfl_up(sc, d);
        if (lane >= d) sc += t;
    }
    if (lane == 63) wsum[wv] = sc;
    __syncthreads();
    int wpre = 0;
#pragma unroll
    for (int j = 0; j < 4; ++j) wpre += (j < wv) ? wsum[j] : 0;
    int run = wpre + sc - s;
#pragma unroll
    for (int j = 0; j < 4; ++j) {
        run += v[j];
        if (base + j < M8) oplus1[base + j] = run;
    }
    if (tid == 255) btot[blockIdx.x] = run;
}

__global__ __launch_bounds__(256) void k_scan_mid(
    const int* __restrict__ btot, int* __restrict__ bbase, int nblk)
{
    __shared__ int sm[512];
    const int tid = threadIdx.x;
    for (int i = tid; i < nblk; i += 256) sm[i] = btot[i];
    __syncthreads();
    if (tid == 0) {
        int run = 0;
        for (int i = 0; i < nblk; ++i) { const int t = sm[i]; sm[i] = run; run += t; }
    }
    __syncthreads();
    for (int i = tid; i < nblk; i += 256) bbase[i] = sm[i];
}

// finalize offsets8 AND init cursor8 (cursor8[i] = offsets8[i])
__global__ __launch_bounds__(256) void k_scan_add(
    int* __restrict__ offsets8, int* __restrict__ cursor8,
    const int* __restrict__ bbase, int M8)
{
    const int base = blockIdx.x * 1024 + threadIdx.x * 4;
    const int b = bbase[blockIdx.x];
#pragma unroll
    for (int j = 0; j < 4; ++j) {
        const int i1 = base + j + 1;            // finalized index
        if (base + j < M8) {
            const int v = offsets8[i1] + b;
            offsets8[i1] = v;
            if (i1 < M8) cursor8[i1] = v;
        }
    }
    if (blockIdx.x == 0 && threadIdx.x == 0) {
        offsets8[0] = 0;
        cursor8[0]  = 0;
    }
}

// fill: ONE 8B scattered store per edge (key|norm packed)
__global__ __launch_bounds__(256) void k_fill8(
    const int* __restrict__ esrc, const int* __restrict__ edst,
    const int* __restrict__ etype, const float* __restrict__ norm,
    int* __restrict__ cursor8, uint2* __restrict__ pedge, int E) {
    const int e = blockIdx.x * 256 + threadIdx.x;
    if (e >= E) return;
    const int t = etype[e];
    const int pos = atomicAdd(&cursor8[edst[e] * 8 + t], 1);
    pedge[pos] = make_uint2((unsigned)(esrc[e] | (t << 27)),
                            __float_as_uint(norm[e]));
}

// ---------------------------------------------------------------------------
// Gather: one wave per dst; bins [r0,r1) contiguous in sorted CSR.
// h bf16; non-atomic out RMW (wave owns row).
// ---------------------------------------------------------------------------
__global__ __launch_bounds__(256) void k_gather(
    const unsigned short* __restrict__ h,   // [r1-r0][N][128] bf16
    const int*   __restrict__ offsets8,     // [N*8+1]
    const uint2* __restrict__ pedge,        // [E]
    float* __restrict__ out,                // [N][128]
    int N, int r0, int r1)
{
    const int wid  = blockIdx.x * 4 + (threadIdx.x >> 6);
    if (wid >= N) return;
    const int lane = threadIdx.x & 63;
    const int s = offsets8[wid * 8 + r0];
    const int e = offsets8[wid * 8 + r1];
    if (e == s) return;
    float2 acc = {0.f, 0.f};
#pragma unroll 4
    for (int p = s; p < e; ++p) {
        const uint2 ed = pedge[p];               // wave-uniform broadcast
        const int key = (int)ed.x;
        const float nm = __uint_as_float(ed.y);
        const int t   = (key >> 27) - r0;
        const int src = key & 0x07FFFFFF;
        const unsigned vp = *(const unsigned*)(
            h + (((size_t)t * N + src) << 7) + lane * 2);
        acc.x = fmaf(bf2f((unsigned short)(vp & 0xFFFF)), nm, acc.x);
        acc.y = fmaf(bf2f((unsigned short)(vp >> 16)),    nm, acc.y);
    }
    float* op = out + ((size_t)wid << 7) + lane * 2;
    const float2 cur = *(const float2*)op;
    *(float2*)op = {cur.x + acc.x, cur.y + acc.y};
}

// ---------------------------------------------------------------------------
extern "C" void kernel_launch(void* const* d_in, const int* in_sizes, int n_in,
                              void* d_out, int out_size, void* d_ws, size_t ws_size,
                              hipStream_t stream) {
    const float* x     = (const float*)d_in[0];
    const int*   esrc  = (const int*)d_in[1];
    const int*   edst  = (const int*)d_in[2];
    const int*   etype = (const int*)d_in[3];
    const float* norm  = (const float*)d_in[4];
    const float* basis = (const float*)d_in[5];
    const float* att   = (const float*)d_in[6];
    const float* root  = (const float*)d_in[7];
    const float* bias  = (const float*)d_in[8];
    float* out = (float*)d_out;

    const int N  = in_sizes[0] / IN_CH;
    const int E  = in_sizes[1];
    const int M8 = N * 8;
    const int nblkA = (M8 + 1023) / 1024;

    // ---- workspace layout ----
    short* wT   = (short*)d_ws;                       // 1.18 MB
    short* xcat = wT + (size_t)9 * OUT_CH * KCAT;     // 51.2 MB
    int* deg8     = (int*)(xcat + (size_t)N * KCAT);  // 1.6 MB
    int* cursor8  = deg8;                             // alias: deg8 dead after scan
    int* offsets8 = deg8 + M8;                        // 1.6 MB (+1)
    int* btot     = offsets8 + M8 + 1;
    int* bbase    = btot + nblkA;
    size_t poff = (size_t)((char*)(bbase + nblkA) - (char*)d_ws);
    poff = (poff + 7) & ~(size_t)7;
    uint2* pedge = (uint2*)((char*)d_ws + poff);      // E*8 = 12.8 MB
    size_t hoff = poff + (size_t)E * 8;
    hoff = (hoff + 255) & ~(size_t)255;
    unsigned short* h = (unsigned short*)((char*)d_ws + hoff);

    const size_t perRel = (size_t)N * OUT_CH * 2;     // 12.8 MB (bf16)
    int CR;                                           // prefer even splits
    {
        const size_t avail = (ws_size > hoff) ? (ws_size - hoff) : 0;
        const size_t fit = avail / perRel;
        if      (fit >= 8) CR = 8;
        else if (fit >= 4) CR = 4;
        else if (fit >= 2) CR = 2;
        else               CR = 1;
    }

    const int nbE  = (E + 255) / 256;
    const int nbM8 = (M8 + 255) / 256;
    const int nbG  = (N + 127) / 128;
    const int gblocks = (N + 3) / 4;

    // 1. weights (hi|lo, transposed) and x split
    k_build_wT<<<(9 * IN_CH * OUT_CH) / 256, 256, 0, stream>>>(att, basis, root, wT);
    k_split_x<<<(N * IN_CH + 255) / 256, 256, 0, stream>>>(x, xcat, N * IN_CH);

    // 2. (dst,type)-sorted CSR with packed edge payload
    k_zero<<<nbM8, 256, 0, stream>>>(deg8, M8);
    k_hist8<<<nbE, 256, 0, stream>>>(edst, etype, deg8, E);
    k_scan_blk<<<nblkA, 256, 0, stream>>>(deg8, offsets8 + 1, btot, M8);
    k_scan_mid<<<1, 256, 0, stream>>>(btot, bbase, nblkA);
    k_scan_add<<<nblkA, 256, 0, stream>>>(offsets8, cursor8, bbase, M8);
    k_fill8<<<nbE, 256, 0, stream>>>(esrc, edst, etype, norm, cursor8, pedge, E);

    if (CR >= NUM_REL) {
        // fused: one k_mm for 8 relations + root; one gather pass
        k_mm<<<dim3(nbG, NUM_REL + 1), 256, 0, stream>>>(
            xcat, wT, bias, out, h, N, NUM_REL);
        k_gather<<<gblocks, 256, 0, stream>>>(
            h, offsets8, pedge, out, N, 0, NUM_REL);
    } else {
        // fallback: root separately, then relation chunks
        k_mm<<<dim3(nbG, 1), 256, 0, stream>>>(
            xcat, wT + (size_t)NUM_REL * OUT_CH * KCAT, bias, out, h, N, 0);
        for (int rr0 = 0; rr0 < NUM_REL; rr0 += CR) {
            const int cr = (NUM_REL - rr0 < CR) ? (NUM_REL - rr0) : CR;
            k_mm<<<dim3(nbG, cr), 256, 0, stream>>>(
                xcat, wT + (size_t)rr0 * OUT_CH * KCAT, bias, out, h, N, -1);
            k_gather<<<gblocks, 256, 0, stream>>>(
                h, offsets8, pedge, out, N, rr0, rr0 + cr);
        }
    }
}

// Round 12
// 432.146 us; speedup vs baseline: 7.5661x; 1.2389x over previous
//
#include <hip/hip_runtime.h>

#define IN_CH 256
#define OUT_CH 128
#define NUM_REL 8
#define NUM_BASES 4
#define KK 256              // K for fp16 GEMM
#define NSTEP 8             // 256 / 32

typedef _Float16 f16x8 __attribute__((ext_vector_type(8)));
typedef _Float16 f16x2 __attribute__((ext_vector_type(2)));
typedef float    f32x4 __attribute__((ext_vector_type(4)));
typedef unsigned short u16x8 __attribute__((ext_vector_type(8)));

typedef const __attribute__((address_space(1))) unsigned int* gas_u32p;
typedef __attribute__((address_space(3))) unsigned int*       las_u32p;
#define GLOAD16(g, l) __builtin_amdgcn_global_load_lds( \
    (gas_u32p)(const void*)(g), (las_u32p)(void*)(l), 16, 0, 0)

__device__ __forceinline__ unsigned short f2h(float f) {
    const _Float16 h = (_Float16)f;               // v_cvt_f16_f32 (RNE)
    return __builtin_bit_cast(unsigned short, h);
}

// ---------------------------------------------------------------------------
// wT[r][o][k] fp16 (transposed weights): r<8 from att*basis, r==8 root.
// ---------------------------------------------------------------------------
__global__ __launch_bounds__(256) void k_build_wT(
    const float* __restrict__ att, const float* __restrict__ basis,
    const float* __restrict__ root, unsigned short* __restrict__ wT)
{
    const int idx = blockIdx.x * 256 + threadIdx.x;   // < 9*32768
    const int r = idx >> 15, io = idx & 32767;
    const int i = io >> 7, o = io & 127;
    float v;
    if (r < NUM_REL) {
        const int S = IN_CH * OUT_CH;
        v = att[r*4+0]*basis[io] + att[r*4+1]*basis[S+io]
          + att[r*4+2]*basis[2*S+io] + att[r*4+3]*basis[3*S+io];
    } else {
        v = root[io];
    }
    wT[((size_t)r * OUT_CH + o) * KK + i] = f2h(v);
}

// ---------------------------------------------------------------------------
// xh[n][k] fp16 = cvt(x), 4 elements/thread
// ---------------------------------------------------------------------------
__global__ __launch_bounds__(256) void k_cvt_x(
    const float* __restrict__ x, unsigned short* __restrict__ xh, int total4)
{
    const int idx = blockIdx.x * 256 + threadIdx.x;
    if (idx >= total4) return;
    const float4 v = *(const float4*)(x + (size_t)idx * 4);
    ushort4 o;
    o.x = f2h(v.x); o.y = f2h(v.y); o.z = f2h(v.z); o.w = f2h(v.w);
    *(ushort4*)(xh + (size_t)idx * 4) = o;
}

// ---------------------------------------------------------------------------
// fp16 MFMA GEMM, double-buffered LDS, one barrier per K-step. 128^2 tile,
// BK=32, 4 waves x 4x4 16x16x32_f16 frags, global_load_lds w16.
// Bank-conflict fix (both-sides XOR swizzle, LDS stays linear for gload_lds):
//   LDS slot (row, s) holds global k-quadrant  qsrc = s ^ ((row>>1)&3);
//   reader wanting (row, q) reads slot  q ^ ((row>>1)&3).
//   Under the fixed-lane-group service model (8 lanes x 16B per clock), each
//   group's granules then sweep all 32 banks exactly once -> conflict-free;
//   under a set-based model it is a no-op (same address multiset). Round 8
//   measured 1.08e7 conflicts = 4 cyc/b128, matching the group model.
// Block blockIdx.y==rootIdx writes f32+bias to Df32; others fp16 to D16.
// ---------------------------------------------------------------------------
__global__ __launch_bounds__(256) void k_mm(
    const unsigned short* __restrict__ xh,   // [N][256] fp16
    const unsigned short* __restrict__ wTb,  // [gridDim.y][128][256] fp16
    const float* __restrict__ bias,
    float* __restrict__ Df32,                // [N][128] (root)
    unsigned short* __restrict__ D16,        // [*][N][128] fp16 (h)
    int N, int rootIdx)
{
    const int rr = blockIdx.y;
    const unsigned short* __restrict__ Wt = wTb + (size_t)rr * OUT_CH * KK;
    const int row0 = blockIdx.x * 128;

    __shared__ unsigned short As[2][128 * 32];   // 2 x 8KB
    __shared__ unsigned short Bs[2][128 * 32];   // 2 x 8KB

    const int tid  = threadIdx.x;
    const int lane = tid & 63;
    const int wv   = tid >> 6;
    const int wr   = wv >> 1;
    const int wc   = wv & 1;
    const int lrow = lane & 15;
    const int q    = lane >> 4;
    const int sw   = (lrow >> 1) & 3;        // read-side swizzle (row-derived)

    f32x4 acc[4][4];
#pragma unroll
    for (int m = 0; m < 4; ++m)
#pragma unroll
        for (int n = 0; n < 4; ++n) acc[m][n] = f32x4{0.f, 0.f, 0.f, 0.f};

    auto STAGE = [&](int b, int s) {
        const int k0 = s * 32;
#pragma unroll
        for (int i = 0; i < 2; ++i) {
            const int c = tid + i * 256;             // 16B chunk 0..511
            const int trow = c >> 2, slot = c & 3;
            const int qsrc = slot ^ ((trow >> 1) & 3);   // source pre-swizzle
            int grow = row0 + trow; if (grow >= N) grow = N - 1;
            GLOAD16(xh + (size_t)grow * KK + k0 + qsrc * 8, &As[b][c * 8]);
            GLOAD16(Wt + (size_t)trow * KK + k0 + qsrc * 8, &Bs[b][c * 8]);
        }
    };

    STAGE(0, 0);
    __syncthreads();                    // drains vmcnt(0): buf0 ready

#pragma unroll 2
    for (int s = 0; s < NSTEP; ++s) {
        const int cur = s & 1;
        if (s + 1 < NSTEP) STAGE(cur ^ 1, s + 1);   // in flight during MFMA

        u16x8 af[4], bg[4];
#pragma unroll
        for (int m = 0; m < 4; ++m)
            af[m] = *(const u16x8*)
                &As[cur][(wr * 64 + m * 16 + lrow) * 32 + ((q ^ sw) * 8)];
#pragma unroll
        for (int n = 0; n < 4; ++n)
            bg[n] = *(const u16x8*)
                &Bs[cur][(wc * 64 + n * 16 + lrow) * 32 + ((q ^ sw) * 8)];
#pragma unroll
        for (int m = 0; m < 4; ++m)
#pragma unroll
            for (int n = 0; n < 4; ++n)
                acc[m][n] = __builtin_amdgcn_mfma_f32_16x16x32_f16(
                    __builtin_bit_cast(f16x8, af[m]),
                    __builtin_bit_cast(f16x8, bg[n]), acc[m][n], 0, 0, 0);

        __syncthreads();   // cur fully consumed + next buf drained
    }

    // C/D layout: col=lane&15, row=(lane>>4)*4+j  [m89; dtype-independent]
    if (rr == rootIdx) {
        float bv[4];
#pragma unroll
        for (int n = 0; n < 4; ++n) bv[n] = bias[wc * 64 + n * 16 + lrow];
#pragma unroll
        for (int m = 0; m < 4; ++m)
#pragma unroll
            for (int j = 0; j < 4; ++j) {
                const int row = row0 + wr * 64 + m * 16 + q * 4 + j;
                if (row < N) {
#pragma unroll
                    for (int n = 0; n < 4; ++n)
                        Df32[(size_t)row * OUT_CH + wc * 64 + n * 16 + lrow] =
                            acc[m][n][j] + bv[n];
                }
            }
    } else {
        unsigned short* __restrict__ Dh = D16 + (size_t)rr * N * OUT_CH;
#pragma unroll
        for (int m = 0; m < 4; ++m)
#pragma unroll
            for (int j = 0; j < 4; ++j) {
                const int row = row0 + wr * 64 + m * 16 + q * 4 + j;
                if (row < N) {
#pragma unroll
                    for (int n = 0; n < 4; ++n)
                        Dh[(size_t)row * OUT_CH + wc * 64 + n * 16 + lrow] =
                            f2h(acc[m][n][j]);
                }
            }
    }
}

// ---------------------------------------------------------------------------
// (dst,type)-binned CSR build over M8 = N*8 bins
// ---------------------------------------------------------------------------
__global__ __launch_bounds__(256) void k_zero(int* __restrict__ p, int n) {
    const int i = blockIdx.x * 256 + threadIdx.x;
    if (i < n) p[i] = 0;
}

__global__ __launch_bounds__(256) void k_hist8(
    const int* __restrict__ edst, const int* __restrict__ etype,
    int* __restrict__ deg8, int E) {
    const int e = blockIdx.x * 256 + threadIdx.x;
    if (e < E) atomicAdd(&deg8[edst[e] * 8 + etype[e]], 1);
}

__global__ __launch_bounds__(256) void k_scan_blk(
    const int* __restrict__ deg, int* __restrict__ oplus1,
    int* __restrict__ btot, int M8)
{
    __shared__ int wsum[4];
    const int tid = threadIdx.x, lane = tid & 63, wv = tid >> 6;
    const int base = blockIdx.x * 1024 + tid * 4;
    int v[4]; int s = 0;
#pragma unroll
    for (int j = 0; j < 4; ++j) {
        v[j] = (base + j < M8) ? deg[base + j] : 0;
        s += v[j];
    }
    int sc = s;
#pragma unroll
    for (int d = 1; d < 64; d <<= 1) {
        const int t = __shfl_up(sc, d);
        if (lane >= d) sc += t;
    }
    if (lane == 63) wsum[wv] = sc;
    __syncthreads();
    int wpre = 0;
#pragma unroll
    for (int j = 0; j < 4; ++j) wpre += (j < wv) ? wsum[j] : 0;
    int run = wpre + sc - s;
#pragma unroll
    for (int j = 0; j < 4; ++j) {
        run += v[j];
        if (base + j < M8) oplus1[base + j] = run;
    }
    if (tid == 255) btot[blockIdx.x] = run;
}

__global__ __launch_bounds__(256) void k_scan_mid(
    const int* __restrict__ btot, int* __restrict__ bbase, int nblk)
{
    __shared__ int sm[512];
    const int tid = threadIdx.x;
    for (int i = tid; i < nblk; i += 256) sm[i] = btot[i];
    __syncthreads();
    if (tid == 0) {
        int run = 0;
        for (int i = 0; i < nblk; ++i) { const int t = sm[i]; sm[i] = run; run += t; }
    }
    __syncthreads();
    for (int i = tid; i < nblk; i += 256) bbase[i] = sm[i];
}

// finalize offsets8 AND init cursor8
__global__ __launch_bounds__(256) void k_scan_add(
    int* __restrict__ offsets8, int* __restrict__ cursor8,
    const int* __restrict__ bbase, int M8)
{
    const int base = blockIdx.x * 1024 + threadIdx.x * 4;
    const int b = bbase[blockIdx.x];
#pragma unroll
    for (int j = 0; j < 4; ++j) {
        const int i1 = base + j + 1;
        if (base + j < M8) {
            const int v = offsets8[i1] + b;
            offsets8[i1] = v;
            if (i1 < M8) cursor8[i1] = v;
        }
    }
    if (blockIdx.x == 0 && threadIdx.x == 0) {
        offsets8[0] = 0;
        cursor8[0]  = 0;
    }
}

// fill: ONE 8B scattered store per edge (key|norm packed)
__global__ __launch_bounds__(256) void k_fill8(
    const int* __restrict__ esrc, const int* __restrict__ edst,
    const int* __restrict__ etype, const float* __restrict__ norm,
    int* __restrict__ cursor8, uint2* __restrict__ pedge, int E) {
    const int e = blockIdx.x * 256 + threadIdx.x;
    if (e >= E) return;
    const int t = etype[e];
    const int pos = atomicAdd(&cursor8[edst[e] * 8 + t], 1);
    pedge[pos] = make_uint2((unsigned)(esrc[e] | (t << 27)),
                            __float_as_uint(norm[e]));
}

// ---------------------------------------------------------------------------
// Gather: one wave per dst; bins [r0,r1) contiguous in sorted CSR.
// h fp16; non-atomic out RMW (wave owns row).
// ---------------------------------------------------------------------------
__global__ __launch_bounds__(256) void k_gather(
    const unsigned short* __restrict__ h,   // [r1-r0][N][128] fp16
    const int*   __restrict__ offsets8,     // [N*8+1]
    const uint2* __restrict__ pedge,        // [E]
    float* __restrict__ out,                // [N][128]
    int N, int r0, int r1)
{
    const int wid  = blockIdx.x * 4 + (threadIdx.x >> 6);
    if (wid >= N) return;
    const int lane = threadIdx.x & 63;
    const int s = offsets8[wid * 8 + r0];
    const int e = offsets8[wid * 8 + r1];
    if (e == s) return;
    float2 acc = {0.f, 0.f};
#pragma unroll 4
    for (int p = s; p < e; ++p) {
        const uint2 ed = pedge[p];               // wave-uniform broadcast
        const int key = (int)ed.x;
        const float nm = __uint_as_float(ed.y);
        const int t   = (key >> 27) - r0;
        const int src = key & 0x07FFFFFF;
        const unsigned vp = *(const unsigned*)(
            h + (((size_t)t * N + src) << 7) + lane * 2);
        const f16x2 hv = __builtin_bit_cast(f16x2, vp);
        acc.x = fmaf((float)hv[0], nm, acc.x);
        acc.y = fmaf((float)hv[1], nm, acc.y);
    }
    float* op = out + ((size_t)wid << 7) + lane * 2;
    const float2 cur = *(const float2*)op;
    *(float2*)op = {cur.x + acc.x, cur.y + acc.y};
}

// ---------------------------------------------------------------------------
extern "C" void kernel_launch(void* const* d_in, const int* in_sizes, int n_in,
                              void* d_out, int out_size, void* d_ws, size_t ws_size,
                              hipStream_t stream) {
    const float* x     = (const float*)d_in[0];
    const int*   esrc  = (const int*)d_in[1];
    const int*   edst  = (const int*)d_in[2];
    const int*   etype = (const int*)d_in[3];
    const float* norm  = (const float*)d_in[4];
    const float* basis = (const float*)d_in[5];
    const float* att   = (const float*)d_in[6];
    const float* root  = (const float*)d_in[7];
    const float* bias  = (const float*)d_in[8];
    float* out = (float*)d_out;

    const int N  = in_sizes[0] / IN_CH;
    const int E  = in_sizes[1];
    const int M8 = N * 8;
    const int nblkA = (M8 + 1023) / 1024;

    // ---- workspace layout ----
    unsigned short* wT = (unsigned short*)d_ws;       // 9*128*256*2 = 0.59 MB
    unsigned short* xh = wT + (size_t)9 * OUT_CH * KK;// 25.6 MB
    int* deg8     = (int*)(xh + (size_t)N * KK);      // 1.6 MB
    int* cursor8  = deg8;                             // alias: deg8 dead after scan
    int* offsets8 = deg8 + M8;                        // 1.6 MB (+1)
    int* btot     = offsets8 + M8 + 1;
    int* bbase    = btot + nblkA;
    size_t poff = (size_t)((char*)(bbase + nblkA) - (char*)d_ws);
    poff = (poff + 7) & ~(size_t)7;
    uint2* pedge = (uint2*)((char*)d_ws + poff);      // E*8 = 12.8 MB
    size_t hoff = poff + (size_t)E * 8;
    hoff = (hoff + 255) & ~(size_t)255;
    unsigned short* h = (unsigned short*)((char*)d_ws + hoff);

    const size_t perRel = (size_t)N * OUT_CH * 2;     // 12.8 MB (fp16)
    int CR;                                           // prefer even splits
    {
        const size_t avail = (ws_size > hoff) ? (ws_size - hoff) : 0;
        const size_t fit = avail / perRel;
        if      (fit >= 8) CR = 8;
        else if (fit >= 4) CR = 4;
        else if (fit >= 2) CR = 2;
        else               CR = 1;
    }

    const int nbE  = (E + 255) / 256;
    const int nbM8 = (M8 + 255) / 256;
    const int nbG  = (N + 127) / 128;
    const int gblocks = (N + 3) / 4;

    // 1. fp16 weights (transposed) and fp16 x
    k_build_wT<<<(9 * IN_CH * OUT_CH) / 256, 256, 0, stream>>>(att, basis, root, wT);
    k_cvt_x<<<(N * IN_CH / 4 + 255) / 256, 256, 0, stream>>>(x, xh, N * IN_CH / 4);

    // 2. (dst,type)-sorted CSR with packed edge payload
    k_zero<<<nbM8, 256, 0, stream>>>(deg8, M8);
    k_hist8<<<nbE, 256, 0, stream>>>(edst, etype, deg8, E);
    k_scan_blk<<<nblkA, 256, 0, stream>>>(deg8, offsets8 + 1, btot, M8);
    k_scan_mid<<<1, 256, 0, stream>>>(btot, bbase, nblkA);
    k_scan_add<<<nblkA, 256, 0, stream>>>(offsets8, cursor8, bbase, M8);
    k_fill8<<<nbE, 256, 0, stream>>>(esrc, edst, etype, norm, cursor8, pedge, E);

    if (CR >= NUM_REL) {
        // fused: one k_mm for 8 relations + root; one gather pass
        k_mm<<<dim3(nbG, NUM_REL + 1), 256, 0, stream>>>(
            xh, wT, bias, out, h, N, NUM_REL);
        k_gather<<<gblocks, 256, 0, stream>>>(
            h, offsets8, pedge, out, N, 0, NUM_REL);
    } else {
        // fallback: root separately, then relation chunks
        k_mm<<<dim3(nbG, 1), 256, 0, stream>>>(
            xh, wT + (size_t)NUM_REL * OUT_CH * KK, bias, out, h, N, 0);
        for (int rr0 = 0; rr0 < NUM_REL; rr0 += CR) {
            const int cr = (NUM_REL - rr0 < CR) ? (NUM_REL - rr0) : CR;
            k_mm<<<dim3(nbG, cr), 256, 0, stream>>>(
                xh, wT + (size_t)rr0 * OUT_CH * KK, bias, out, h, N, -1);
            k_gather<<<gblocks, 256, 0, stream>>>(
                h, offsets8, pedge, out, N, rr0, rr0 + cr);
        }
    }
}

// Round 13
// 409.897 us; speedup vs baseline: 7.9768x; 1.0543x over previous
//
#include <hip/hip_runtime.h>

#define IN_CH 256
#define OUT_CH 128
#define NUM_REL 8
#define NUM_BASES 4
#define KK 256              // K for fp16 GEMM
#define NSTEP 8             // 256 / 32
#define NBSH 7              // coarse bucket = 128 dst nodes
#define EPB 4096            // edges per k_binA block

typedef _Float16 f16x8 __attribute__((ext_vector_type(8)));
typedef _Float16 f16x2 __attribute__((ext_vector_type(2)));
typedef float    f32x4 __attribute__((ext_vector_type(4)));
typedef unsigned short u16x8 __attribute__((ext_vector_type(8)));

typedef const __attribute__((address_space(1))) unsigned int* gas_u32p;
typedef __attribute__((address_space(3))) unsigned int*       las_u32p;
#define GLOAD16(g, l) __builtin_amdgcn_global_load_lds( \
    (gas_u32p)(const void*)(g), (las_u32p)(void*)(l), 16, 0, 0)

__device__ __forceinline__ unsigned short f2h(float f) {
    const _Float16 h = (_Float16)f;               // v_cvt_f16_f32 (RNE)
    return __builtin_bit_cast(unsigned short, h);
}

// ---------------------------------------------------------------------------
// wT[r][o][k] fp16 (transposed weights): r<8 from att*basis, r==8 root.
// ---------------------------------------------------------------------------
__global__ __launch_bounds__(256) void k_build_wT(
    const float* __restrict__ att, const float* __restrict__ basis,
    const float* __restrict__ root, unsigned short* __restrict__ wT)
{
    const int idx = blockIdx.x * 256 + threadIdx.x;   // < 9*32768
    const int r = idx >> 15, io = idx & 32767;
    const int i = io >> 7, o = io & 127;
    float v;
    if (r < NUM_REL) {
        const int S = IN_CH * OUT_CH;
        v = att[r*4+0]*basis[io] + att[r*4+1]*basis[S+io]
          + att[r*4+2]*basis[2*S+io] + att[r*4+3]*basis[3*S+io];
    } else {
        v = root[io];
    }
    wT[((size_t)r * OUT_CH + o) * KK + i] = f2h(v);
}

// ---------------------------------------------------------------------------
// xh[n][k] fp16 = cvt(x), 4 elements/thread
// ---------------------------------------------------------------------------
__global__ __launch_bounds__(256) void k_cvt_x(
    const float* __restrict__ x, unsigned short* __restrict__ xh, int total4)
{
    const int idx = blockIdx.x * 256 + threadIdx.x;
    if (idx >= total4) return;
    const float4 v = *(const float4*)(x + (size_t)idx * 4);
    ushort4 o;
    o.x = f2h(v.x); o.y = f2h(v.y); o.z = f2h(v.z); o.w = f2h(v.w);
    *(ushort4*)(xh + (size_t)idx * 4) = o;
}

// ---------------------------------------------------------------------------
// fp16 MFMA GEMM (unchanged from round 12; passed @432us, k_mm <= 102us).
// ---------------------------------------------------------------------------
__global__ __launch_bounds__(256) void k_mm(
    const unsigned short* __restrict__ xh,   // [N][256] fp16
    const unsigned short* __restrict__ wTb,  // [gridDim.y][128][256] fp16
    const float* __restrict__ bias,
    float* __restrict__ Df32,                // [N][128] (root)
    unsigned short* __restrict__ D16,        // [*][N][128] fp16 (h)
    int N, int rootIdx)
{
    const int rr = blockIdx.y;
    const unsigned short* __restrict__ Wt = wTb + (size_t)rr * OUT_CH * KK;
    const int row0 = blockIdx.x * 128;

    __shared__ unsigned short As[2][128 * 32];
    __shared__ unsigned short Bs[2][128 * 32];

    const int tid  = threadIdx.x;
    const int lane = tid & 63;
    const int wv   = tid >> 6;
    const int wr   = wv >> 1;
    const int wc   = wv & 1;
    const int lrow = lane & 15;
    const int q    = lane >> 4;
    const int sw   = (lrow >> 1) & 3;        // read-side swizzle (row-derived)

    f32x4 acc[4][4];
#pragma unroll
    for (int m = 0; m < 4; ++m)
#pragma unroll
        for (int n = 0; n < 4; ++n) acc[m][n] = f32x4{0.f, 0.f, 0.f, 0.f};

    auto STAGE = [&](int b, int s) {
        const int k0 = s * 32;
#pragma unroll
        for (int i = 0; i < 2; ++i) {
            const int c = tid + i * 256;
            const int trow = c >> 2, slot = c & 3;
            const int qsrc = slot ^ ((trow >> 1) & 3);
            int grow = row0 + trow; if (grow >= N) grow = N - 1;
            GLOAD16(xh + (size_t)grow * KK + k0 + qsrc * 8, &As[b][c * 8]);
            GLOAD16(Wt + (size_t)trow * KK + k0 + qsrc * 8, &Bs[b][c * 8]);
        }
    };

    STAGE(0, 0);
    __syncthreads();

#pragma unroll 2
    for (int s = 0; s < NSTEP; ++s) {
        const int cur = s & 1;
        if (s + 1 < NSTEP) STAGE(cur ^ 1, s + 1);

        u16x8 af[4], bg[4];
#pragma unroll
        for (int m = 0; m < 4; ++m)
            af[m] = *(const u16x8*)
                &As[cur][(wr * 64 + m * 16 + lrow) * 32 + ((q ^ sw) * 8)];
#pragma unroll
        for (int n = 0; n < 4; ++n)
            bg[n] = *(const u16x8*)
                &Bs[cur][(wc * 64 + n * 16 + lrow) * 32 + ((q ^ sw) * 8)];
#pragma unroll
        for (int m = 0; m < 4; ++m)
#pragma unroll
            for (int n = 0; n < 4; ++n)
                acc[m][n] = __builtin_amdgcn_mfma_f32_16x16x32_f16(
                    __builtin_bit_cast(f16x8, af[m]),
                    __builtin_bit_cast(f16x8, bg[n]), acc[m][n], 0, 0, 0);

        __syncthreads();
    }

    if (rr == rootIdx) {
        float bv[4];
#pragma unroll
        for (int n = 0; n < 4; ++n) bv[n] = bias[wc * 64 + n * 16 + lrow];
#pragma unroll
        for (int m = 0; m < 4; ++m)
#pragma unroll
            for (int j = 0; j < 4; ++j) {
                const int row = row0 + wr * 64 + m * 16 + q * 4 + j;
                if (row < N) {
#pragma unroll
                    for (int n = 0; n < 4; ++n)
                        Df32[(size_t)row * OUT_CH + wc * 64 + n * 16 + lrow] =
                            acc[m][n][j] + bv[n];
                }
            }
    } else {
        unsigned short* __restrict__ Dh = D16 + (size_t)rr * N * OUT_CH;
#pragma unroll
        for (int m = 0; m < 4; ++m)
#pragma unroll
            for (int j = 0; j < 4; ++j) {
                const int row = row0 + wr * 64 + m * 16 + q * 4 + j;
                if (row < N) {
#pragma unroll
                    for (int n = 0; n < 4; ++n)
                        Dh[(size_t)row * OUT_CH + wc * 64 + n * 16 + lrow] =
                            f2h(acc[m][n][j]);
                }
            }
    }
}

// ---------------------------------------------------------------------------
// Two-level counting sort of edges by dst (coarse bucket = dst>>7).
// Record packing (N < 65536): w0 = src | (t<<16) | (dstLocal<<19); w1 = norm.
// ---------------------------------------------------------------------------
__global__ __launch_bounds__(256) void k_zero(int* __restrict__ p, int n) {
    const int i = blockIdx.x * 256 + threadIdx.x;
    if (i < n) p[i] = 0;
}

// coarse histogram, LDS-aggregated (<=512 global atomics per block)
__global__ __launch_bounds__(256) void k_histB(
    const int* __restrict__ edst, int* __restrict__ bhist, int E, int NB)
{
    __shared__ int lh[512];
    const int tid = threadIdx.x;
    for (int i = tid; i < 512; i += 256) lh[i] = 0;
    __syncthreads();
    const int base = blockIdx.x * EPB;
#pragma unroll
    for (int k = 0; k < EPB / 256; ++k) {
        const int e = base + k * 256 + tid;
        if (e < E) atomicAdd(&lh[edst[e] >> NBSH], 1);
    }
    __syncthreads();
    for (int i = tid; i < NB; i += 256) {
        const int c = lh[i];
        if (c) atomicAdd(&bhist[i], c);
    }
}

// exclusive scan of NB (<512) bucket counts; init cursor = base
__global__ __launch_bounds__(256) void k_scanB(
    const int* __restrict__ bhist, int* __restrict__ bucketBase,
    int* __restrict__ bucketCursor, int NB)
{
    __shared__ int sm[513];
    const int tid = threadIdx.x;
    for (int i = tid; i < NB; i += 256) sm[i] = bhist[i];
    __syncthreads();
    if (tid == 0) {
        int run = 0;
        for (int i = 0; i < NB; ++i) { const int t = sm[i]; sm[i] = run; run += t; }
        sm[NB] = run;
    }
    __syncthreads();
    for (int i = tid; i <= NB; i += 256) bucketBase[i] = sm[i];
    for (int i = tid; i < NB; i += 256) bucketCursor[i] = sm[i];
}

// pass A: block-aggregated reserve + slice write (line-dense)
__global__ __launch_bounds__(256) void k_binA(
    const int* __restrict__ esrc, const int* __restrict__ edst,
    const int* __restrict__ etype, const float* __restrict__ norm,
    int* __restrict__ bucketCursor, uint2* __restrict__ pedgeA, int E)
{
    __shared__ int lh[512], resBase[512], lcur[512];
    const int tid = threadIdx.x;
    for (int i = tid; i < 512; i += 256) { lh[i] = 0; lcur[i] = 0; }
    __syncthreads();
    const int base = blockIdx.x * EPB;
    uint2 rec[EPB / 256];
    int   bkt[EPB / 256];
#pragma unroll
    for (int k = 0; k < EPB / 256; ++k) {
        const int e = base + k * 256 + tid;
        if (e < E) {
            const int d = edst[e];
            bkt[k] = d >> NBSH;
            rec[k] = make_uint2(
                (unsigned)(esrc[e] | (etype[e] << 16) | ((d & 127) << 19)),
                __float_as_uint(norm[e]));
            atomicAdd(&lh[bkt[k]], 1);
        } else bkt[k] = -1;
    }
    __syncthreads();
    for (int i = tid; i < 512; i += 256) {
        const int c = lh[i];
        if (c) resBase[i] = atomicAdd(&bucketCursor[i], c);
    }
    __syncthreads();
#pragma unroll
    for (int k = 0; k < EPB / 256; ++k) {
        if (bkt[k] >= 0) {
            const int r = atomicAdd(&lcur[bkt[k]], 1);
            pedgeA[resBase[bkt[k]] + r] = rec[k];
        }
    }
}

// pass B: per-bucket local sort by dst, write offsetsN + final pedgeB
__global__ __launch_bounds__(256) void k_binB(
    const uint2* __restrict__ pedgeA, const int* __restrict__ bucketBase,
    int* __restrict__ offsetsN, uint2* __restrict__ pedgeB, int N, int E)
{
    __shared__ int lh[128], lbase[128], lcur[128];
    const int tid = threadIdx.x;
    const int b = blockIdx.x;
    const int s = bucketBase[b], e = bucketBase[b + 1];
    if (tid < 128) { lh[tid] = 0; lcur[tid] = 0; }
    __syncthreads();
    for (int p = s + tid; p < e; p += 256)
        atomicAdd(&lh[(pedgeA[p].x >> 19) & 127], 1);
    __syncthreads();
    if (tid == 0) {
        int run = s;
        for (int j = 0; j < 128; ++j) { const int c = lh[j]; lbase[j] = run; run += c; }
    }
    __syncthreads();
    const int n0 = b << NBSH;
    if (tid < 128 && n0 + tid < N) offsetsN[n0 + tid] = lbase[tid];
    if (b == gridDim.x - 1 && tid == 0) offsetsN[N] = E;
    for (int p = s + tid; p < e; p += 256) {
        const uint2 r = pedgeA[p];
        const int j = (r.x >> 19) & 127;
        const int rk = atomicAdd(&lcur[j], 1);
        pedgeB[lbase[j] + rk] = make_uint2(
            (r.x & 0xFFFF) | (((r.x >> 16) & 7) << 27), r.y);
    }
}

// ---------------------------------------------------------------------------
// Gather: one wave per dst; per-dst range contiguous in dst-sorted pedgeB.
// h fp16; non-atomic out RMW (wave owns row). Type filter only active in
// the CR<8 fallback (fused path: r0=0, r1=8 -> never taken).
// ---------------------------------------------------------------------------
__global__ __launch_bounds__(256) void k_gather(
    const unsigned short* __restrict__ h,   // [r1-r0][N][128] fp16
    const int*   __restrict__ offsetsN,     // [N+1]
    const uint2* __restrict__ pedge,        // [E]
    float* __restrict__ out,                // [N][128]
    int N, int r0, int r1)
{
    const int wid  = blockIdx.x * 4 + (threadIdx.x >> 6);
    if (wid >= N) return;
    const int lane = threadIdx.x & 63;
    const int s = offsetsN[wid];
    const int e = offsetsN[wid + 1];
    if (e == s) return;
    float2 acc = {0.f, 0.f};
#pragma unroll 4
    for (int p = s; p < e; ++p) {
        const uint2 ed = pedge[p];               // sequential within bin
        const int key = (int)ed.x;
        const int t   = key >> 27;
        if (t < r0 || t >= r1) continue;         // wave-uniform
        const float nm = __uint_as_float(ed.y);
        const int src = key & 0x07FFFFFF;
        const unsigned vp = *(const unsigned*)(
            h + (((size_t)(t - r0) * N + src) << 7) + lane * 2);
        const f16x2 hv = __builtin_bit_cast(f16x2, vp);
        acc.x = fmaf((float)hv[0], nm, acc.x);
        acc.y = fmaf((float)hv[1], nm, acc.y);
    }
    float* op = out + ((size_t)wid << 7) + lane * 2;
    const float2 cur = *(const float2*)op;
    *(float2*)op = {cur.x + acc.x, cur.y + acc.y};
}

// ---------------------------------------------------------------------------
extern "C" void kernel_launch(void* const* d_in, const int* in_sizes, int n_in,
                              void* d_out, int out_size, void* d_ws, size_t ws_size,
                              hipStream_t stream) {
    const float* x     = (const float*)d_in[0];
    const int*   esrc  = (const int*)d_in[1];
    const int*   edst  = (const int*)d_in[2];
    const int*   etype = (const int*)d_in[3];
    const float* norm  = (const float*)d_in[4];
    const float* basis = (const float*)d_in[5];
    const float* att   = (const float*)d_in[6];
    const float* root  = (const float*)d_in[7];
    const float* bias  = (const float*)d_in[8];
    float* out = (float*)d_out;

    const int N  = in_sizes[0] / IN_CH;
    const int E  = in_sizes[1];
    const int NB = (N + (1 << NBSH) - 1) >> NBSH;     // coarse buckets (<=512)
    const int nbBin = (E + EPB - 1) / EPB;

    // ---- workspace layout ----
    unsigned short* wT = (unsigned short*)d_ws;       // 0.59 MB
    unsigned short* xh = wT + (size_t)9 * OUT_CH * KK;// 25.6 MB
    int* bhist        = (int*)(xh + (size_t)N * KK);
    int* bucketBase   = bhist + NB;                   // NB+1
    int* bucketCursor = bucketBase + NB + 1;          // NB
    int* offsetsN     = bucketCursor + NB;            // N+1
    size_t poff = (size_t)((char*)(offsetsN + N + 1) - (char*)d_ws);
    poff = (poff + 7) & ~(size_t)7;
    uint2* pedgeA = (uint2*)((char*)d_ws + poff);     // E*8 = 12.8 MB
    uint2* pedgeB = pedgeA + E;                       // E*8 = 12.8 MB
    size_t hoff = poff + (size_t)E * 16;
    hoff = (hoff + 255) & ~(size_t)255;
    unsigned short* h = (unsigned short*)((char*)d_ws + hoff);

    const size_t perRel = (size_t)N * OUT_CH * 2;     // 12.8 MB (fp16)
    int CR;
    {
        const size_t avail = (ws_size > hoff) ? (ws_size - hoff) : 0;
        const size_t fit = avail / perRel;
        if      (fit >= 8) CR = 8;
        else if (fit >= 4) CR = 4;
        else if (fit >= 2) CR = 2;
        else               CR = 1;
    }

    const int nbG = (N + 127) / 128;
    const int gblocks = (N + 3) / 4;

    // 1. fp16 weights (transposed) and fp16 x
    k_build_wT<<<(9 * IN_CH * OUT_CH) / 256, 256, 0, stream>>>(att, basis, root, wT);
    k_cvt_x<<<(N * IN_CH / 4 + 255) / 256, 256, 0, stream>>>(x, xh, N * IN_CH / 4);

    // 2. dst-sorted edge array via two-level counting sort
    k_zero<<<(NB + 255) / 256, 256, 0, stream>>>(bhist, NB);
    k_histB<<<nbBin, 256, 0, stream>>>(edst, bhist, E, NB);
    k_scanB<<<1, 256, 0, stream>>>(bhist, bucketBase, bucketCursor, NB);
    k_binA<<<nbBin, 256, 0, stream>>>(esrc, edst, etype, norm,
                                      bucketCursor, pedgeA, E);
    k_binB<<<NB, 256, 0, stream>>>(pedgeA, bucketBase, offsetsN, pedgeB, N, E);

    if (CR >= NUM_REL) {
        // fused: one k_mm for 8 relations + root; one gather pass
        k_mm<<<dim3(nbG, NUM_REL + 1), 256, 0, stream>>>(
            xh, wT, bias, out, h, N, NUM_REL);
        k_gather<<<gblocks, 256, 0, stream>>>(
            h, offsetsN, pedgeB, out, N, 0, NUM_REL);
    } else {
        // fallback: root separately, then relation chunks (type-filtered gather)
        k_mm<<<dim3(nbG, 1), 256, 0, stream>>>(
            xh, wT + (size_t)NUM_REL * OUT_CH * KK, bias, out, h, N, 0);
        for (int rr0 = 0; rr0 < NUM_REL; rr0 += CR) {
            const int cr = (NUM_REL - rr0 < CR) ? (NUM_REL - rr0) : CR;
            k_mm<<<dim3(nbG, cr), 256, 0, stream>>>(
                xh, wT + (size_t)rr0 * OUT_CH * KK, bias, out, h, N, -1);
            k_gather<<<gblocks, 256, 0, stream>>>(
                h, offsetsN, pedgeB, out, N, rr0, rr0 + cr);
        }
    }
}